// Round 1
// baseline (834.032 us; speedup 1.0000x reference)
//
#include <hip/hip_runtime.h>
#include <hip/hip_bf16.h>
#include <cstddef>

// Problem constants
constexpr int B = 32, E = 30000, D = 200, L = 50;
constexpr int KX = D + L;      // 250
constexpr int KPAD = 256;      // padded K for gate GEMM

// ---------------------------------------------------------------------------
// K_sums: e2p_sum[b] = sum_e e2m*prob ; inv_sum[b] = sum_e (1 - e2m)
// ---------------------------------------------------------------------------
__global__ __launch_bounds__(256) void sums_kernel(
    const int* __restrict__ e2m, const float* __restrict__ prob,
    float* __restrict__ psum, float* __restrict__ isum)
{
    int b = blockIdx.x, tid = threadIdx.x;
    const int*   mrow = e2m  + (size_t)b * E;
    const float* prow = prob + (size_t)b * E;
    float sp = 0.f, si = 0.f;
    for (int e = tid; e < E; e += 256) {
        float m = (float)mrow[e];
        sp = fmaf(m, prow[e], sp);
        si += (1.f - m);
    }
    #pragma unroll
    for (int off = 32; off >= 1; off >>= 1) {
        sp += __shfl_down(sp, off);
        si += __shfl_down(si, off);
    }
    __shared__ float rp[4], ri[4];
    if ((tid & 63) == 0) { rp[tid >> 6] = sp; ri[tid >> 6] = si; }
    __syncthreads();
    if (tid == 0) {
        psum[b] = rp[0] + rp[1] + rp[2] + rp[3];
        isum[b] = ri[0] + ri[1] + ri[2] + ri[3];
    }
}

// ---------------------------------------------------------------------------
// K1: gate GEMM  -> e2_emb[E][D]
//   x = [emb_e ; num_lit]  (K = 250, padded 256)
//   pre1[d] = x . Wg[d,:]          (mat0)
//   pre2[d] = emb.W1[d,:] + lit.W2[d,:]  (mat1)
//   e2_emb  = (1-sig(pre2+gb))*emb + sig(pre2+gb)*tanh(pre1+bg)
// Tile: BM=128 rows x BN=32 d-cols (x2 mats), BK=64, 256 thr, micro 8r x 2d x 2m
// ---------------------------------------------------------------------------
constexpr int BM = 128, BN = 32, BK = 64;

__global__ __launch_bounds__(256) void gate_kernel(
    const float* __restrict__ emb_e, const float* __restrict__ num_lit,
    const float* __restrict__ Wg, const float* __restrict__ bg,
    const float* __restrict__ W1, const float* __restrict__ W2,
    const float* __restrict__ gbias, float* __restrict__ e2_emb)
{
    __shared__ float Xs[BM][BK + 1];      // 128 x 65
    __shared__ float Ws[BK][2 * BN + 2];  // 64 x 66 (cols 0..31 mat0, 32..63 mat1)

    const int tid = threadIdx.x;
    const int tx = tid & 15;        // col group: d = d0 + tx*2 + j
    const int ty = tid >> 4;        // row group: rows ty*8 .. +7
    const int e0 = blockIdx.x * BM;
    const int d0 = blockIdx.y * BN;

    float acc1[8][2] = {};  // mat0 (g_emb pre)
    float acc2[8][2] = {};  // mat1 (g pre)

    for (int kk = 0; kk < KPAD; kk += BK) {
        // ---- stage X tile (128 x 64), coalesced on k ----
        #pragma unroll
        for (int r = 0; r < 32; ++r) {
            int idx = tid + r * 256;         // 0..8191
            int row = idx >> 6, col = idx & 63;
            int e = e0 + row, k = kk + col;
            float v = 0.f;
            if (e < E) {
                if (k < D)       v = emb_e[(size_t)e * D + k];
                else if (k < KX) v = num_lit[(size_t)e * L + (k - D)];
            }
            Xs[row][col] = v;
        }
        // ---- stage W tile (64k x 64c), coalesced on k ----
        #pragma unroll
        for (int r = 0; r < 16; ++r) {
            int idx = tid + r * 256;         // 0..4095
            int c = idx >> 6, k = idx & 63;
            int kg = kk + k;
            float v = 0.f;
            if (c < BN) {
                int d = d0 + c;
                if (d < D && kg < KX) v = Wg[(size_t)d * KX + kg];
            } else {
                int d = d0 + c - BN;
                if (d < D) {
                    if (kg < D)       v = W1[(size_t)d * D + kg];
                    else if (kg < KX) v = W2[(size_t)d * L + (kg - D)];
                }
            }
            Ws[k][c] = v;
        }
        __syncthreads();

        #pragma unroll 8
        for (int k = 0; k < BK; ++k) {
            float a[8], b1[2], b2[2];
            #pragma unroll
            for (int i = 0; i < 8; ++i) a[i] = Xs[ty * 8 + i][k];
            b1[0] = Ws[k][tx * 2];      b1[1] = Ws[k][tx * 2 + 1];
            b2[0] = Ws[k][BN + tx * 2]; b2[1] = Ws[k][BN + tx * 2 + 1];
            #pragma unroll
            for (int i = 0; i < 8; ++i) {
                acc1[i][0] = fmaf(a[i], b1[0], acc1[i][0]);
                acc1[i][1] = fmaf(a[i], b1[1], acc1[i][1]);
                acc2[i][0] = fmaf(a[i], b2[0], acc2[i][0]);
                acc2[i][1] = fmaf(a[i], b2[1], acc2[i][1]);
            }
        }
        __syncthreads();
    }

    // ---- epilogue: gate combine ----
    #pragma unroll
    for (int i = 0; i < 8; ++i) {
        int e = e0 + ty * 8 + i;
        if (e >= E) continue;
        #pragma unroll
        for (int j = 0; j < 2; ++j) {
            int d = d0 + tx * 2 + j;
            if (d >= D) continue;
            float pre1 = acc1[i][j] + bg[d];
            float pre2 = acc2[i][j] + gbias[d];
            float g = 1.f / (1.f + expf(-pre2));
            float t = tanhf(pre1);
            float emb = emb_e[(size_t)e * D + d];
            e2_emb[(size_t)e * D + d] = (1.f - g) * emb + g * t;
        }
    }
}

// ---------------------------------------------------------------------------
// K_q: q[b][d] = e2_emb[e1[b]][d] + emb_rel[rel[b]][d]   (e1_emb == gate row)
// ---------------------------------------------------------------------------
__global__ __launch_bounds__(256) void q_kernel(
    const int* __restrict__ e1, const int* __restrict__ rel,
    const float* __restrict__ emb_rel, const float* __restrict__ e2_emb,
    float* __restrict__ q)
{
    int tid = threadIdx.x;
    for (int idx = tid; idx < B * D; idx += 256) {
        int b = idx / D, d = idx % D;
        q[idx] = e2_emb[(size_t)e1[b] * D + d] + emb_rel[(size_t)rel[b] * D + d];
    }
}

// ---------------------------------------------------------------------------
// K2: GEMV partials.  chunk = 128 e per block, 235 blocks.
//   cP = e2m*prob ; cN = (1-e2m)*drop*2
//   partialP[blk][b][d] = sum_{e in chunk} cP[b][e]*e2_emb[e][d]  (same for N)
// 256 thr: bgrp=tid&7 (4 b's), dgrp=tid>>3 (8 d's, active dgrp<25)
// ---------------------------------------------------------------------------
constexpr int CH = 128;
constexpr int NB2 = (E + CH - 1) / CH;   // 235

__global__ __launch_bounds__(256) void gemv_kernel(
    const int* __restrict__ e2m, const float* __restrict__ prob,
    const float* __restrict__ drop, const float* __restrict__ e2_emb,
    float* __restrict__ pP, float* __restrict__ pN)
{
    __shared__ float cPN[CH][33][2];
    const int tid = threadIdx.x;
    const int e0 = blockIdx.x * CH;

    // stage coefficients (coalesced on e)
    #pragma unroll
    for (int r = 0; r < 16; ++r) {
        int idx = tid + r * 256;          // 0..4095
        int b = idx >> 7, ei = idx & 127;
        int e = e0 + ei;
        float cp = 0.f, cn = 0.f;
        if (e < E) {
            size_t o = (size_t)b * E + e;
            float m = (float)e2m[o];
            cp = m * prob[o];
            cn = (1.f - m) * drop[o] * 2.f;
        }
        cPN[ei][b][0] = cp;
        cPN[ei][b][1] = cn;
    }
    __syncthreads();

    const int bgrp = tid & 7, dgrp = tid >> 3;
    if (dgrp >= 25) return;               // no further barriers
    const int b0 = bgrp * 4, d0 = dgrp * 8;

    float aP[4][8] = {}, aN[4][8] = {};
    #pragma unroll 2
    for (int ei = 0; ei < CH; ++ei) {
        int e = e0 + ei;
        if (e > E - 1) e = E - 1;         // coeffs are 0 there
        const float* ep = e2_emb + (size_t)e * D + d0;
        float4 m0 = *(const float4*)ep;
        float4 m1 = *(const float4*)(ep + 4);
        #pragma unroll
        for (int i = 0; i < 4; ++i) {
            float cp = cPN[ei][b0 + i][0];
            float cn = cPN[ei][b0 + i][1];
            aP[i][0] = fmaf(cp, m0.x, aP[i][0]); aP[i][1] = fmaf(cp, m0.y, aP[i][1]);
            aP[i][2] = fmaf(cp, m0.z, aP[i][2]); aP[i][3] = fmaf(cp, m0.w, aP[i][3]);
            aP[i][4] = fmaf(cp, m1.x, aP[i][4]); aP[i][5] = fmaf(cp, m1.y, aP[i][5]);
            aP[i][6] = fmaf(cp, m1.z, aP[i][6]); aP[i][7] = fmaf(cp, m1.w, aP[i][7]);
            aN[i][0] = fmaf(cn, m0.x, aN[i][0]); aN[i][1] = fmaf(cn, m0.y, aN[i][1]);
            aN[i][2] = fmaf(cn, m0.z, aN[i][2]); aN[i][3] = fmaf(cn, m0.w, aN[i][3]);
            aN[i][4] = fmaf(cn, m1.x, aN[i][4]); aN[i][5] = fmaf(cn, m1.y, aN[i][5]);
            aN[i][6] = fmaf(cn, m1.z, aN[i][6]); aN[i][7] = fmaf(cn, m1.w, aN[i][7]);
        }
    }

    float* outP = pP + (size_t)blockIdx.x * (B * D);
    float* outN = pN + (size_t)blockIdx.x * (B * D);
    #pragma unroll
    for (int i = 0; i < 4; ++i)
        #pragma unroll
        for (int j = 0; j < 8; ++j) {
            outP[(b0 + i) * D + d0 + j] = aP[i][j];
            outN[(b0 + i) * D + d0 + j] = aN[i][j];
        }
}

// ---------------------------------------------------------------------------
// K2r: reduce partials -> pos_vec/neg_vec (12800 outputs, coalesced)
// ---------------------------------------------------------------------------
__global__ __launch_bounds__(128) void reduce_kernel(
    const float* __restrict__ pP, const float* __restrict__ pN,
    float* __restrict__ posv, float* __restrict__ negv)
{
    int o = blockIdx.x * 128 + threadIdx.x;   // 0..12799
    float sp = 0.f, sn = 0.f;
    #pragma unroll 4
    for (int p = 0; p < NB2; ++p) {
        sp += pP[(size_t)p * (B * D) + o];
        sn += pN[(size_t)p * (B * D) + o];
    }
    posv[o] = sp;
    negv[o] = sn;
}

// ---------------------------------------------------------------------------
// K4: pred[b][e] = sigmoid(9 - sum_d |q[b][d] - e2_emb[e][d]|)
// Block: 32 b x 64 e, 128 thr (bgrp=tid&7 -> 4b, egrp=tid>>3 -> 4e).
// LDS pad 201 -> all tile reads conflict-free.
// ---------------------------------------------------------------------------
__global__ __launch_bounds__(128) void score_kernel(
    const float* __restrict__ q, const float* __restrict__ e2_emb,
    float* __restrict__ pred)
{
    __shared__ float Qs[B][201];
    __shared__ float Es[64][201];
    const int tid = threadIdx.x;
    const int e0 = blockIdx.x * 64;

    for (int idx = tid; idx < B * D; idx += 128)
        Qs[idx / D][idx % D] = q[idx];
    for (int idx = tid; idx < 64 * D; idx += 128) {
        int r = idx / D, c = idx % D;
        int e = e0 + r;
        Es[r][c] = (e < E) ? e2_emb[(size_t)e * D + c] : 0.f;
    }
    __syncthreads();

    const int bgrp = tid & 7, egrp = tid >> 3;
    float acc[4][4] = {};
    #pragma unroll 4
    for (int d = 0; d < D; ++d) {
        float qa[4], eb[4];
        #pragma unroll
        for (int i = 0; i < 4; ++i) qa[i] = Qs[bgrp * 4 + i][d];
        #pragma unroll
        for (int j = 0; j < 4; ++j) eb[j] = Es[egrp * 4 + j][d];
        #pragma unroll
        for (int i = 0; i < 4; ++i)
            #pragma unroll
            for (int j = 0; j < 4; ++j)
                acc[i][j] += fabsf(qa[i] - eb[j]);
    }

    #pragma unroll
    for (int i = 0; i < 4; ++i) {
        int b = bgrp * 4 + i;
        #pragma unroll
        for (int j = 0; j < 4; ++j) {
            int e = e0 + egrp * 4 + j;
            if (e < E) {
                float s = 9.0f - acc[i][j];
                pred[(size_t)b * E + e] = 1.f / (1.f + expf(-s));
            }
        }
    }
}

// ---------------------------------------------------------------------------
// K5: means -> pos_s/neg_s -> loss (one block)
// thread = b*8 + dl ; each handles 25 d's, shfl-reduce width 8
// ---------------------------------------------------------------------------
__global__ __launch_bounds__(256) void final_kernel(
    const int* __restrict__ e1, const float* __restrict__ q,
    const float* __restrict__ posv, const float* __restrict__ negv,
    const float* __restrict__ psum, const float* __restrict__ isum,
    const float* __restrict__ e2_emb, float* __restrict__ loss_out)
{
    const int tid = threadIdx.x;
    const int b = tid >> 3, dl = tid & 7;
    const int e1b = e1[b];
    const float isp = 1.f / psum[b];
    const float isn = 1.f / isum[b];
    float ps = 0.f, ns = 0.f;
    #pragma unroll
    for (int t = 0; t < 25; ++t) {
        int d = dl * 25 + t;
        float e1e = e2_emb[(size_t)e1b * D + d];
        float pm = 0.3f * (posv[b * D + d] * isp) + 0.7f * e1e;  // ALPHA=0.3
        float nm = 0.7f * (negv[b * D + d] * isn) + 0.3f * e1e;  // BETA=0.7
        float qv = q[b * D + d];
        ps += fabsf(qv - pm);
        ns += fabsf(qv - nm);
    }
    ps += __shfl_down(ps, 4, 8); ps += __shfl_down(ps, 2, 8); ps += __shfl_down(ps, 1, 8);
    ns += __shfl_down(ns, 4, 8); ns += __shfl_down(ns, 2, 8); ns += __shfl_down(ns, 1, 8);

    __shared__ float PS[B], NS[B];
    if (dl == 0) { PS[b] = ps; NS[b] = ns; }
    __syncthreads();

    // loss = -mean_{i,j} log_sigmoid(NS[j] - PS[i]) over 32x32
    float part = 0.f;
    #pragma unroll
    for (int r = 0; r < 4; ++r) {
        int idx = tid + r * 256;
        int i = idx >> 5, j = idx & 31;
        float x = NS[j] - PS[i];
        part += fminf(x, 0.f) - log1pf(expf(-fabsf(x)));
    }
    #pragma unroll
    for (int off = 32; off >= 1; off >>= 1) part += __shfl_down(part, off);
    __shared__ float wr[4];
    if ((tid & 63) == 0) wr[tid >> 6] = part;
    __syncthreads();
    if (tid == 0) loss_out[0] = -(wr[0] + wr[1] + wr[2] + wr[3]) * (1.f / 1024.f);
}

// ---------------------------------------------------------------------------
extern "C" void kernel_launch(void* const* d_in, const int* in_sizes, int n_in,
                              void* d_out, int out_size, void* d_ws, size_t ws_size,
                              hipStream_t stream)
{
    const int*   e1      = (const int*)d_in[0];
    const int*   rel     = (const int*)d_in[1];
    const int*   e2m     = (const int*)d_in[2];
    const float* emb_e   = (const float*)d_in[3];
    const float* emb_rel = (const float*)d_in[4];
    const float* num_lit = (const float*)d_in[5];
    const float* Wg      = (const float*)d_in[6];
    const float* bg      = (const float*)d_in[7];
    const float* W1      = (const float*)d_in[8];
    const float* W2      = (const float*)d_in[9];
    const float* gbias   = (const float*)d_in[10];
    const float* prob    = (const float*)d_in[11];
    const float* drop    = (const float*)d_in[12];

    float* pred = (float*)d_out;                 // [B*E] then loss at [B*E]
    float* ws   = (float*)d_ws;

    // workspace layout (floats); total 12,035,264 fl = 48.2 MB
    float* e2_emb = ws;                          // 6,000,000
    float* q      = ws + 6000000;                // 6,400
    float* pP     = ws + 6006400;                // 235*12800 = 3,008,000
    float* pN     = ws + 9014400;                // 3,008,000
    float* posv   = ws + 12022400;               // 6,400
    float* negv   = ws + 12028800;               // 6,400
    float* psum   = ws + 12035200;               // 32
    float* isum   = ws + 12035232;               // 32

    sums_kernel<<<B, 256, 0, stream>>>(e2m, prob, psum, isum);
    gate_kernel<<<dim3((E + BM - 1) / BM, (D + BN - 1) / BN), 256, 0, stream>>>(
        emb_e, num_lit, Wg, bg, W1, W2, gbias, e2_emb);
    q_kernel<<<1, 256, 0, stream>>>(e1, rel, emb_rel, e2_emb, q);
    gemv_kernel<<<NB2, 256, 0, stream>>>(e2m, prob, drop, e2_emb, pP, pN);
    reduce_kernel<<<(B * D) / 128, 128, 0, stream>>>(pP, pN, posv, negv);
    score_kernel<<<(E + 63) / 64, 128, 0, stream>>>(q, e2_emb, pred);
    final_kernel<<<1, 256, 0, stream>>>(e1, q, posv, negv, psum, isum, e2_emb,
                                        pred + (size_t)B * E);
}

// Round 2
// 589.265 us; speedup vs baseline: 1.4154x; 1.4154x over previous
//
#include <hip/hip_runtime.h>
#include <hip/hip_bf16.h>
#include <cstddef>

// Problem constants
constexpr int B = 32, E = 30000, D = 200, L = 50;
constexpr int KX = D + L;      // 250
constexpr int KPAD = 256;      // padded K for gate GEMM

__device__ __forceinline__ float sigmoidf_(float x) { return 1.f / (1.f + __expf(-x)); }
__device__ __forceinline__ float tanhf_(float x) {
    // tanh via exp(-2|x|): no overflow, monotone, accurate for the small preacts here
    float t = __expf(-2.f * fabsf(x));
    float r = (1.f - t) / (1.f + t);
    return copysignf(r, x);
}

// ---------------------------------------------------------------------------
// K_sums: e2p_sum[b] = sum_e e2m*prob ; inv_sum[b] = sum_e (1 - e2m)
// ---------------------------------------------------------------------------
__global__ __launch_bounds__(256) void sums_kernel(
    const int* __restrict__ e2m, const float* __restrict__ prob,
    float* __restrict__ psum, float* __restrict__ isum)
{
    int b = blockIdx.x, tid = threadIdx.x;
    const int*   mrow = e2m  + (size_t)b * E;
    const float* prow = prob + (size_t)b * E;
    float sp = 0.f, si = 0.f;
    for (int e = tid; e < E; e += 256) {
        float m = (float)mrow[e];
        sp = fmaf(m, prow[e], sp);
        si += (1.f - m);
    }
    #pragma unroll
    for (int off = 32; off >= 1; off >>= 1) {
        sp += __shfl_down(sp, off);
        si += __shfl_down(si, off);
    }
    __shared__ float rp[4], ri[4];
    if ((tid & 63) == 0) { rp[tid >> 6] = sp; ri[tid >> 6] = si; }
    __syncthreads();
    if (tid == 0) {
        psum[b] = rp[0] + rp[1] + rp[2] + rp[3];
        isum[b] = ri[0] + ri[1] + ri[2] + ri[3];
    }
}

// ---------------------------------------------------------------------------
// K1: gate GEMM -> e2_emb[E][D]   (v2: all-b128 LDS, swizzled X tile)
//   BM=256 rows x 64 cols (32 d x 2 mats), BK=32, 256 thr, micro 8r x 8c.
//   Xs[row][k] stored as float4 groups XOR-swizzled by (row>>3)&7 so the 8
//   rows co-read in one ds_read_b128 instruction hit 8 distinct 16B slots.
//   Ws pitch 68 floats: 16B-aligned rows, 2-way read conflict (free).
// ---------------------------------------------------------------------------
constexpr int GBM = 256, GBK = 32;

__global__ __launch_bounds__(256) void gate_kernel(
    const float* __restrict__ emb_e, const float* __restrict__ num_lit,
    const float* __restrict__ Wg, const float* __restrict__ bg,
    const float* __restrict__ W1, const float* __restrict__ W2,
    const float* __restrict__ gbias, float* __restrict__ e2_emb)
{
    __shared__ __align__(16) float Xs[GBM * GBK];   // 32 KB, swizzled
    __shared__ __align__(16) float Ws[GBK * 68];    // 8.5 KB

    const int tid = threadIdx.x;
    const int tx = tid & 7;        // col group: cols tx*8 .. +7 (4 d x 2 mats)
    const int ty = tid >> 3;       // row group: rows ty*8 .. +7
    const int e0 = blockIdx.x * GBM;
    const int d0 = blockIdx.y * 32;
    const int tyk = ty & 7;        // swizzle key for reads

    float acc[8][8] = {};

    for (int kk = 0; kk < KPAD; kk += GBK) {
        // ---- stage X tile: 256 rows x 32 k as float4s, XOR-swizzled ----
        #pragma unroll
        for (int r = 0; r < 8; ++r) {
            int idx = tid + r * 256;          // 0..2047
            int row = idx >> 3, k4 = idx & 7;
            int e = e0 + row, k = kk + k4 * 4;
            float4 v = make_float4(0.f, 0.f, 0.f, 0.f);
            if (e < E) {
                if (k + 3 < D) {
                    v = *(const float4*)(emb_e + (size_t)e * D + k);
                } else if (k >= D && k + 3 < KX) {
                    const float2* p = (const float2*)(num_lit + (size_t)e * L + (k - D));
                    float2 p0 = p[0], p1 = p[1];
                    v = make_float4(p0.x, p0.y, p1.x, p1.y);
                } else if (k < KX) {          // mixed / partial tail
                    float t0[4];
                    #pragma unroll
                    for (int j = 0; j < 4; ++j) {
                        int kj = k + j;
                        t0[j] = (kj < D)  ? emb_e[(size_t)e * D + kj]
                              : (kj < KX) ? num_lit[(size_t)e * L + (kj - D)] : 0.f;
                    }
                    v = make_float4(t0[0], t0[1], t0[2], t0[3]);
                }
            }
            int slot = k4 ^ ((row >> 3) & 7);
            *(float4*)&Xs[row * GBK + (slot << 2)] = v;
        }
        // ---- stage W tile: 32 k x 64 cols (coalesced along k) ----
        #pragma unroll
        for (int r = 0; r < 8; ++r) {
            int idx = tid + r * 256;          // 0..2047
            int kl = idx & 31, c = idx >> 5;  // c 0..63
            int kg = kk + kl;
            int d = d0 + (c >> 1);
            float v = 0.f;
            if (d < D) {
                if ((c & 1) == 0) {
                    if (kg < KX) v = Wg[(size_t)d * KX + kg];
                } else {
                    if (kg < D)       v = W1[(size_t)d * D + kg];
                    else if (kg < KX) v = W2[(size_t)d * L + (kg - D)];
                }
            }
            Ws[kl * 68 + c] = v;
        }
        __syncthreads();

        for (int k4 = 0; k4 < 8; ++k4) {
            float4 a4[8];
            #pragma unroll
            for (int i = 0; i < 8; ++i)
                a4[i] = *(const float4*)&Xs[(ty * 8 + i) * GBK + ((k4 ^ tyk) << 2)];
            #pragma unroll
            for (int j = 0; j < 4; ++j) {
                int kl = k4 * 4 + j;
                float4 blo = *(const float4*)&Ws[kl * 68 + tx * 8];
                float4 bhi = *(const float4*)&Ws[kl * 68 + tx * 8 + 4];
                #pragma unroll
                for (int i = 0; i < 8; ++i) {
                    float av = (j == 0) ? a4[i].x : (j == 1) ? a4[i].y
                             : (j == 2) ? a4[i].z : a4[i].w;
                    acc[i][0] = fmaf(av, blo.x, acc[i][0]);
                    acc[i][1] = fmaf(av, blo.y, acc[i][1]);
                    acc[i][2] = fmaf(av, blo.z, acc[i][2]);
                    acc[i][3] = fmaf(av, blo.w, acc[i][3]);
                    acc[i][4] = fmaf(av, bhi.x, acc[i][4]);
                    acc[i][5] = fmaf(av, bhi.y, acc[i][5]);
                    acc[i][6] = fmaf(av, bhi.z, acc[i][6]);
                    acc[i][7] = fmaf(av, bhi.w, acc[i][7]);
                }
            }
        }
        __syncthreads();
    }

    // ---- epilogue: gate combine.  cols tx*8+cc -> d = d0+tx*4+(cc>>1), mat=cc&1
    #pragma unroll
    for (int i = 0; i < 8; ++i) {
        int e = e0 + ty * 8 + i;
        if (e >= E) continue;
        #pragma unroll
        for (int p = 0; p < 4; ++p) {
            int d = d0 + tx * 4 + p;
            if (d >= D) continue;
            float pre1 = acc[i][2 * p]     + bg[d];
            float pre2 = acc[i][2 * p + 1] + gbias[d];
            float g = sigmoidf_(pre2);
            float t = tanhf_(pre1);
            float emb = emb_e[(size_t)e * D + d];
            e2_emb[(size_t)e * D + d] = (1.f - g) * emb + g * t;
        }
    }
}

// ---------------------------------------------------------------------------
// K_q: q[b][d] = e2_emb[e1[b]][d] + emb_rel[rel[b]][d]
// ---------------------------------------------------------------------------
__global__ __launch_bounds__(256) void q_kernel(
    const int* __restrict__ e1, const int* __restrict__ rel,
    const float* __restrict__ emb_rel, const float* __restrict__ e2_emb,
    float* __restrict__ q)
{
    int tid = threadIdx.x;
    for (int idx = tid; idx < B * D; idx += 256) {
        int b = idx / D, d = idx % D;
        q[idx] = e2_emb[(size_t)e1[b] * D + d] + emb_rel[(size_t)rel[b] * D + d];
    }
}

// ---------------------------------------------------------------------------
// K2: GEMV partials (unchanged structure).
// ---------------------------------------------------------------------------
constexpr int CH = 128;
constexpr int NB2 = (E + CH - 1) / CH;   // 235

__global__ __launch_bounds__(256) void gemv_kernel(
    const int* __restrict__ e2m, const float* __restrict__ prob,
    const float* __restrict__ drop, const float* __restrict__ e2_emb,
    float* __restrict__ pP, float* __restrict__ pN)
{
    __shared__ float cPN[CH][33][2];
    const int tid = threadIdx.x;
    const int e0 = blockIdx.x * CH;

    #pragma unroll
    for (int r = 0; r < 16; ++r) {
        int idx = tid + r * 256;
        int b = idx >> 7, ei = idx & 127;
        int e = e0 + ei;
        float cp = 0.f, cn = 0.f;
        if (e < E) {
            size_t o = (size_t)b * E + e;
            float m = (float)e2m[o];
            cp = m * prob[o];
            cn = (1.f - m) * drop[o] * 2.f;
        }
        cPN[ei][b][0] = cp;
        cPN[ei][b][1] = cn;
    }
    __syncthreads();

    const int bgrp = tid & 7, dgrp = tid >> 3;
    if (dgrp >= 25) return;
    const int b0 = bgrp * 4, d0 = dgrp * 8;

    float aP[4][8] = {}, aN[4][8] = {};
    #pragma unroll 2
    for (int ei = 0; ei < CH; ++ei) {
        int e = e0 + ei;
        if (e > E - 1) e = E - 1;
        const float* ep = e2_emb + (size_t)e * D + d0;
        float4 m0 = *(const float4*)ep;
        float4 m1 = *(const float4*)(ep + 4);
        #pragma unroll
        for (int i = 0; i < 4; ++i) {
            float cp = cPN[ei][b0 + i][0];
            float cn = cPN[ei][b0 + i][1];
            aP[i][0] = fmaf(cp, m0.x, aP[i][0]); aP[i][1] = fmaf(cp, m0.y, aP[i][1]);
            aP[i][2] = fmaf(cp, m0.z, aP[i][2]); aP[i][3] = fmaf(cp, m0.w, aP[i][3]);
            aP[i][4] = fmaf(cp, m1.x, aP[i][4]); aP[i][5] = fmaf(cp, m1.y, aP[i][5]);
            aP[i][6] = fmaf(cp, m1.z, aP[i][6]); aP[i][7] = fmaf(cp, m1.w, aP[i][7]);
            aN[i][0] = fmaf(cn, m0.x, aN[i][0]); aN[i][1] = fmaf(cn, m0.y, aN[i][1]);
            aN[i][2] = fmaf(cn, m0.z, aN[i][2]); aN[i][3] = fmaf(cn, m0.w, aN[i][3]);
            aN[i][4] = fmaf(cn, m1.x, aN[i][4]); aN[i][5] = fmaf(cn, m1.y, aN[i][5]);
            aN[i][6] = fmaf(cn, m1.z, aN[i][6]); aN[i][7] = fmaf(cn, m1.w, aN[i][7]);
        }
    }

    float* outP = pP + (size_t)blockIdx.x * (B * D);
    float* outN = pN + (size_t)blockIdx.x * (B * D);
    #pragma unroll
    for (int i = 0; i < 4; ++i)
        #pragma unroll
        for (int j = 0; j < 8; ++j) {
            outP[(b0 + i) * D + d0 + j] = aP[i][j];
            outN[(b0 + i) * D + d0 + j] = aN[i][j];
        }
}

// ---------------------------------------------------------------------------
// K2r: reduce partials -> pos_vec/neg_vec
// ---------------------------------------------------------------------------
__global__ __launch_bounds__(128) void reduce_kernel(
    const float* __restrict__ pP, const float* __restrict__ pN,
    float* __restrict__ posv, float* __restrict__ negv)
{
    int o = blockIdx.x * 128 + threadIdx.x;
    float sp = 0.f, sn = 0.f;
    #pragma unroll 4
    for (int p = 0; p < NB2; ++p) {
        sp += pP[(size_t)p * (B * D) + o];
        sn += pN[(size_t)p * (B * D) + o];
    }
    posv[o] = sp;
    negv[o] = sn;
}

// ---------------------------------------------------------------------------
// K4 (v3): pred[b][e] = sigmoid(9 - sum_d |q[b][d] - e2_emb[e][d]|)
//   Block: 32 b x 128 e, 256 thr.  q fragments held in registers per 8-d
//   chunk (LDS pitch 204: b128-aligned, 4-way conflict only on these reads);
//   e2_emb streamed straight from global (L1/L2 dedupes the 8x b-group reuse).
//   No per-chunk barriers -> VALU-bound.
// ---------------------------------------------------------------------------
__global__ __launch_bounds__(256) void score_kernel(
    const float* __restrict__ q, const float* __restrict__ e2_emb,
    float* __restrict__ pred)
{
    __shared__ __align__(16) float Qs[B * 204];
    const int tid = threadIdx.x;
    const int e0 = blockIdx.x * 128;

    for (int i = tid; i < B * D; i += 256) {
        int b = i / D, d = i - b * D;
        Qs[b * 204 + d] = q[i];
    }
    __syncthreads();

    const int bgrp = tid & 7, egrp = tid >> 3;
    const int b0 = bgrp * 4;
    const int ebase = e0 + egrp * 4;

    float acc[4][4] = {};
    for (int dc = 0; dc < D; dc += 8) {
        float4 qlo[4], qhi[4];
        #pragma unroll
        for (int i = 0; i < 4; ++i) {
            qlo[i] = *(const float4*)&Qs[(b0 + i) * 204 + dc];
            qhi[i] = *(const float4*)&Qs[(b0 + i) * 204 + dc + 4];
        }
        #pragma unroll
        for (int j = 0; j < 4; ++j) {
            int e = ebase + j; if (e >= E) e = E - 1;
            const float* ep = e2_emb + (size_t)e * D + dc;
            float4 lo = *(const float4*)ep;
            float4 hi = *(const float4*)(ep + 4);
            #pragma unroll
            for (int i = 0; i < 4; ++i) {
                float s = fabsf(qlo[i].x - lo.x);
                s += fabsf(qlo[i].y - lo.y);
                s += fabsf(qlo[i].z - lo.z);
                s += fabsf(qlo[i].w - lo.w);
                s += fabsf(qhi[i].x - hi.x);
                s += fabsf(qhi[i].y - hi.y);
                s += fabsf(qhi[i].z - hi.z);
                s += fabsf(qhi[i].w - hi.w);
                acc[i][j] += s;
            }
        }
    }

    #pragma unroll
    for (int i = 0; i < 4; ++i) {
        int b = b0 + i;
        float4 o;
        o.x = sigmoidf_(9.0f - acc[i][0]);
        o.y = sigmoidf_(9.0f - acc[i][1]);
        o.z = sigmoidf_(9.0f - acc[i][2]);
        o.w = sigmoidf_(9.0f - acc[i][3]);
        if (ebase + 3 < E) {
            *(float4*)&pred[(size_t)b * E + ebase] = o;
        } else {
            float ov[4] = {o.x, o.y, o.z, o.w};
            #pragma unroll
            for (int j = 0; j < 4; ++j)
                if (ebase + j < E) pred[(size_t)b * E + ebase + j] = ov[j];
        }
    }
}

// ---------------------------------------------------------------------------
// K5: means -> pos_s/neg_s -> loss (one block)
// ---------------------------------------------------------------------------
__global__ __launch_bounds__(256) void final_kernel(
    const int* __restrict__ e1, const float* __restrict__ q,
    const float* __restrict__ posv, const float* __restrict__ negv,
    const float* __restrict__ psum, const float* __restrict__ isum,
    const float* __restrict__ e2_emb, float* __restrict__ loss_out)
{
    const int tid = threadIdx.x;
    const int b = tid >> 3, dl = tid & 7;
    const int e1b = e1[b];
    const float isp = 1.f / psum[b];
    const float isn = 1.f / isum[b];
    float ps = 0.f, ns = 0.f;
    #pragma unroll
    for (int t = 0; t < 25; ++t) {
        int d = dl * 25 + t;
        float e1e = e2_emb[(size_t)e1b * D + d];
        float pm = 0.3f * (posv[b * D + d] * isp) + 0.7f * e1e;
        float nm = 0.7f * (negv[b * D + d] * isn) + 0.3f * e1e;
        float qv = q[b * D + d];
        ps += fabsf(qv - pm);
        ns += fabsf(qv - nm);
    }
    ps += __shfl_down(ps, 4, 8); ps += __shfl_down(ps, 2, 8); ps += __shfl_down(ps, 1, 8);
    ns += __shfl_down(ns, 4, 8); ns += __shfl_down(ns, 2, 8); ns += __shfl_down(ns, 1, 8);

    __shared__ float PS[B], NS[B];
    if (dl == 0) { PS[b] = ps; NS[b] = ns; }
    __syncthreads();

    float part = 0.f;
    #pragma unroll
    for (int r = 0; r < 4; ++r) {
        int idx = tid + r * 256;
        int i = idx >> 5, j = idx & 31;
        float x = NS[j] - PS[i];
        part += fminf(x, 0.f) - log1pf(expf(-fabsf(x)));
    }
    #pragma unroll
    for (int off = 32; off >= 1; off >>= 1) part += __shfl_down(part, off);
    __shared__ float wr[4];
    if ((tid & 63) == 0) wr[tid >> 6] = part;
    __syncthreads();
    if (tid == 0) loss_out[0] = -(wr[0] + wr[1] + wr[2] + wr[3]) * (1.f / 1024.f);
}

// ---------------------------------------------------------------------------
extern "C" void kernel_launch(void* const* d_in, const int* in_sizes, int n_in,
                              void* d_out, int out_size, void* d_ws, size_t ws_size,
                              hipStream_t stream)
{
    const int*   e1      = (const int*)d_in[0];
    const int*   rel     = (const int*)d_in[1];
    const int*   e2m     = (const int*)d_in[2];
    const float* emb_e   = (const float*)d_in[3];
    const float* emb_rel = (const float*)d_in[4];
    const float* num_lit = (const float*)d_in[5];
    const float* Wg      = (const float*)d_in[6];
    const float* bg      = (const float*)d_in[7];
    const float* W1      = (const float*)d_in[8];
    const float* W2      = (const float*)d_in[9];
    const float* gbias   = (const float*)d_in[10];
    const float* prob    = (const float*)d_in[11];
    const float* drop    = (const float*)d_in[12];

    float* pred = (float*)d_out;
    float* ws   = (float*)d_ws;

    float* e2_emb = ws;                          // 6,000,000
    float* q      = ws + 6000000;                // 6,400
    float* pP     = ws + 6006400;                // 3,008,000
    float* pN     = ws + 9014400;                // 3,008,000
    float* posv   = ws + 12022400;               // 6,400
    float* negv   = ws + 12028800;               // 6,400
    float* psum   = ws + 12035200;               // 32
    float* isum   = ws + 12035232;               // 32

    sums_kernel<<<B, 256, 0, stream>>>(e2m, prob, psum, isum);
    gate_kernel<<<dim3((E + GBM - 1) / GBM, 7), 256, 0, stream>>>(
        emb_e, num_lit, Wg, bg, W1, W2, gbias, e2_emb);
    q_kernel<<<1, 256, 0, stream>>>(e1, rel, emb_rel, e2_emb, q);
    gemv_kernel<<<NB2, 256, 0, stream>>>(e2m, prob, drop, e2_emb, pP, pN);
    reduce_kernel<<<(B * D) / 128, 128, 0, stream>>>(pP, pN, posv, negv);
    score_kernel<<<(E + 127) / 128, 256, 0, stream>>>(q, e2_emb, pred);
    final_kernel<<<1, 256, 0, stream>>>(e1, q, posv, negv, psum, isum, e2_emb,
                                        pred + (size_t)B * E);
}

// Round 5
// 357.867 us; speedup vs baseline: 2.3306x; 1.6466x over previous
//
#include <hip/hip_runtime.h>
#include <hip/hip_bf16.h>
#include <cstddef>

constexpr int B = 32, E = 30000, D = 200, L = 50;

using short8 = __attribute__((ext_vector_type(8))) short;
using f32x4  = __attribute__((ext_vector_type(4))) float;

__device__ __forceinline__ float sigmoidf_(float x){ return 1.f/(1.f+__expf(-x)); }
__device__ __forceinline__ float tanhf_(float x){
    float t = __expf(-2.f*fabsf(x));
    return copysignf((1.f-t)/(1.f+t), x);
}
// round-to-nearest-even f32 -> bf16 bits
__device__ __forceinline__ unsigned short f2bf(float x){
    unsigned u = __float_as_uint(x);
    u += 0x7fffu + ((u>>16)&1u);
    return (unsigned short)(u>>16);
}
__device__ __forceinline__ float bf2f(unsigned short h){
    return __uint_as_float(((unsigned)h)<<16);
}

// ---------------------------------------------------------------------------
// W-prep: build W' hi/lo bf16 planes in MFMA B-fragment order.
//   n = mat*208 + d  (416 cols = 26 n-tiles of 16); k padded to 256.
//   elem(nt,ks,lane,j) = W[n = nt*16+(lane&15)][k = ks*32+((lane>>4)&3)*8+j]
// ---------------------------------------------------------------------------
constexpr int NT_W = 26;
constexpr int WELEMS = NT_W*8*64*8;  // 106496

__global__ __launch_bounds__(256) void wprep_kernel(
    const float* __restrict__ Wg, const float* __restrict__ W1,
    const float* __restrict__ W2,
    unsigned short* __restrict__ whi, unsigned short* __restrict__ wlo)
{
    int idx = blockIdx.x*256 + threadIdx.x;
    if (idx >= WELEMS) return;
    int j = idx & 7, l = (idx>>3)&63, ks = (idx>>9)&7, nt = idx>>12;
    int n = nt*16 + (l&15);
    int k = ks*32 + ((l>>4)&3)*8 + j;
    float v = 0.f;
    if (n < 208) {                       // mat0: Wg (g_emb pre)
        int d = n;
        if (d < 200 && k < 250) v = Wg[d*250 + k];
    } else {                             // mat1: W1|W2 (gate pre)
        int d = n - 208;
        if (d < 200) {
            if (k < 200)      v = W1[d*200 + k];
            else if (k < 250) v = W2[d*50 + (k-200)];
        }
    }
    unsigned short h = f2bf(v);
    whi[idx] = h;
    wlo[idx] = f2bf(v - bf2f(h));
}

// ---------------------------------------------------------------------------
// K_sums
// ---------------------------------------------------------------------------
__global__ __launch_bounds__(256) void sums_kernel(
    const int* __restrict__ e2m, const float* __restrict__ prob,
    float* __restrict__ psum, float* __restrict__ isum)
{
    int b = blockIdx.x, tid = threadIdx.x;
    const int*   mrow = e2m  + (size_t)b * E;
    const float* prow = prob + (size_t)b * E;
    float sp = 0.f, si = 0.f;
    for (int e = tid; e < E; e += 256) {
        float m = (float)mrow[e];
        sp = fmaf(m, prow[e], sp);
        si += (1.f - m);
    }
    #pragma unroll
    for (int off = 32; off >= 1; off >>= 1) {
        sp += __shfl_down(sp, off);
        si += __shfl_down(si, off);
    }
    __shared__ float rp[4], ri[4];
    if ((tid & 63) == 0) { rp[tid >> 6] = sp; ri[tid >> 6] = si; }
    __syncthreads();
    if (tid == 0) {
        psum[b] = rp[0] + rp[1] + rp[2] + rp[3];
        isum[b] = ri[0] + ri[1] + ri[2] + ri[3];
    }
}

// ---------------------------------------------------------------------------
// Gate GEMM via MFMA bf16 hi/lo split (3 mfma): near-fp32 accuracy.
//   Block: 128 rows (8 waves x 16-row m-tile), 416 n in acc (26 f32x4).
//   K-loop: 4 chunks of 64; A staged to LDS in frag layout; W' from global
//   (L1/L2-resident, coalesced 1KB loads).
// ---------------------------------------------------------------------------
__global__ __launch_bounds__(512, 2) void gate_kernel(
    const float* __restrict__ emb_e, const float* __restrict__ num_lit,
    const unsigned short* __restrict__ whi, const unsigned short* __restrict__ wlo,
    const float* __restrict__ bg, const float* __restrict__ gbias,
    float* __restrict__ e2_emb)
{
    __shared__ unsigned short Ah[8192];  // [mt8][ks2][lane64][j8]
    __shared__ unsigned short Al[8192];
    const int tid = threadIdx.x;
    const int lane = tid & 63;
    const int mt = tid >> 6;             // wave id = m-tile
    const int e0 = blockIdx.x * 128;

    f32x4 acc[26];
    #pragma unroll
    for (int i = 0; i < 26; ++i) acc[i] = (f32x4){0.f,0.f,0.f,0.f};

    const int srow = tid >> 2, skq = tid & 3;   // staging: row, 16-k quad
    const int se = e0 + srow;

    for (int c = 0; c < 4; ++c) {
        // ---- read 16 k of X for this row (issue before barrier: overlap) ----
        float v[16];
        if (se < E) {
            #pragma unroll
            for (int s4 = 0; s4 < 4; ++s4) {
                int k = c*64 + skq*16 + s4*4;
                float4 f;
                if (k + 3 < 200) {
                    f = *(const float4*)(emb_e + (size_t)se*200 + k);
                } else if (k >= 200 && k + 3 < 250) {
                    f = *(const float4*)(num_lit + (size_t)se*50 + (k-200));
                } else {
                    float t0[4];
                    #pragma unroll
                    for (int z = 0; z < 4; ++z) {
                        int kz = k + z;
                        t0[z] = kz < 200 ? emb_e[(size_t)se*200 + kz]
                              : kz < 250 ? num_lit[(size_t)se*50 + (kz-200)] : 0.f;
                    }
                    f = make_float4(t0[0], t0[1], t0[2], t0[3]);
                }
                v[s4*4+0]=f.x; v[s4*4+1]=f.y; v[s4*4+2]=f.z; v[s4*4+3]=f.w;
            }
        } else {
            #pragma unroll
            for (int s = 0; s < 16; ++s) v[s] = 0.f;
        }
        if (c) __syncthreads();          // WAR vs previous chunk's frag reads
        #pragma unroll
        for (int g = 0; g < 2; ++g) {    // two contiguous 8-k runs -> b128 writes
            int ks = skq >> 1;
            int lp = (skq*2 + g) & 3;
            int wl_ = (srow & 15) | (lp << 4);
            int off = (((srow >> 4)*2 + ks)*64 + wl_)*8;
            short8 hv, lv;
            #pragma unroll
            for (int z = 0; z < 8; ++z) {
                float x = v[g*8 + z];
                unsigned short h = f2bf(x);
                hv[z] = (short)h;
                lv[z] = (short)f2bf(x - bf2f(h));
            }
            *(short8*)&Ah[off] = hv;
            *(short8*)&Al[off] = lv;
        }
        __syncthreads();

        // ---- MFMA: A frags from LDS, B frags from global W' ----
        short8 xh[2], xl[2];
        #pragma unroll
        for (int ks = 0; ks < 2; ++ks) {
            int off = ((mt*2 + ks)*64 + lane)*8;
            xh[ks] = *(const short8*)&Ah[off];
            xl[ks] = *(const short8*)&Al[off];
        }
        #pragma unroll
        for (int nt = 0; nt < 26; ++nt) {
            #pragma unroll
            for (int ks = 0; ks < 2; ++ks) {
                size_t boff = (size_t)((nt*8 + c*2 + ks)*64 + lane)*8;
                short8 wh = *(const short8*)(whi + boff);
                short8 wv = *(const short8*)(wlo + boff);
                acc[nt] = __builtin_amdgcn_mfma_f32_16x16x32_bf16(xh[ks], wh, acc[nt], 0, 0, 0);
                acc[nt] = __builtin_amdgcn_mfma_f32_16x16x32_bf16(xl[ks], wh, acc[nt], 0, 0, 0);
                acc[nt] = __builtin_amdgcn_mfma_f32_16x16x32_bf16(xh[ks], wv, acc[nt], 0, 0, 0);
            }
        }
    }

    // ---- epilogue: pre1 = acc[nt], pre2 = acc[nt+13]; gate combine ----
    const int col = lane & 15, rg = lane >> 4;
    #pragma unroll
    for (int nt = 0; nt < 13; ++nt) {
        int d = nt*16 + col;
        if (d >= 200) continue;
        float bgd = bg[d], gbd = gbias[d];
        #pragma unroll
        for (int r = 0; r < 4; ++r) {
            int e = e0 + mt*16 + rg*4 + r;
            if (e >= E) continue;
            float pre1 = acc[nt][r] + bgd;
            float pre2 = acc[nt+13][r] + gbd;
            float g = sigmoidf_(pre2);
            float t = tanhf_(pre1);
            float emb = emb_e[(size_t)e*200 + d];
            e2_emb[(size_t)e*200 + d] = (1.f - g)*emb + g*t;
        }
    }
}

// ---------------------------------------------------------------------------
// K_q
// ---------------------------------------------------------------------------
__global__ __launch_bounds__(256) void q_kernel(
    const int* __restrict__ e1, const int* __restrict__ rel,
    const float* __restrict__ emb_rel, const float* __restrict__ e2_emb,
    float* __restrict__ q)
{
    int tid = threadIdx.x;
    for (int idx = tid; idx < B * D; idx += 256) {
        int b = idx / D, d = idx % D;
        q[idx] = e2_emb[(size_t)e1[b] * D + d] + emb_rel[(size_t)rel[b] * D + d];
    }
}

// ---------------------------------------------------------------------------
// GEMV via MFMA: pos/neg weighted sums over entities (split-K over e).
//   118 blocks x 256 e each; per block 4 chunks of 64 e staged to LDS as
//   B-frags; A = bf16 coefficients computed on the fly. Output: f32 partials.
// ---------------------------------------------------------------------------
constexpr int GVB = 118;

__global__ __launch_bounds__(256) void gemv_kernel(
    const int* __restrict__ e2m, const float* __restrict__ prob,
    const float* __restrict__ drop, const float* __restrict__ e2_emb,
    float* __restrict__ gpart)
{
    __shared__ unsigned short Bf[13312];   // [nt13][ks2][lane64][j8]
    const int tid = threadIdx.x, lane = tid & 63, w = tid >> 6;
    const int e0 = blockIdx.x * 256;

    f32x4 acc[2][2][4];
    #pragma unroll
    for (int a = 0; a < 2; ++a)
        #pragma unroll
        for (int m = 0; m < 2; ++m)
            #pragma unroll
            for (int s = 0; s < 4; ++s) acc[a][m][s] = (f32x4){0.f,0.f,0.f,0.f};

    for (int c = 0; c < 4; ++c) {
        int ec = e0 + c*64;
        if (c) __syncthreads();
        // stage e2 chunk (64 e x 208 d, zero-padded) into frag layout
        for (int s = tid; s < 3328; s += 256) {   // 64 * 52 float4-slots
            int el = s / 52, d4 = (s - el*52)*4;
            int e = ec + el;
            float4 f = make_float4(0.f,0.f,0.f,0.f);
            if (e < E && d4 < 200) f = *(const float4*)(e2_emb + (size_t)e*200 + d4);
            int ks = el >> 5, lp = (el >> 3) & 3, j = el & 7;
            float fv[4] = {f.x, f.y, f.z, f.w};
            #pragma unroll
            for (int z = 0; z < 4; ++z) {
                int d = d4 + z;
                Bf[(((d >> 4)*2 + ks)*64 + ((d & 15) | (lp << 4)))*8 + j] = f2bf(fv[z]);
            }
        }
        __syncthreads();

        #pragma unroll
        for (int ks = 0; ks < 2; ++ks) {
            short8 cp8[2], cn8[2];
            #pragma unroll
            for (int mtb = 0; mtb < 2; ++mtb) {
                int b = mtb*16 + (lane & 15);
                int eb = ec + ks*32 + (lane >> 4)*8;
                size_t base = (size_t)b*E + eb;
                #pragma unroll
                for (int j = 0; j < 8; ++j) {
                    float cp = 0.f, cn = 0.f;
                    if (eb + j < E) {
                        int   m  = e2m[base + j];
                        float p  = prob[base + j];
                        float dr = drop[base + j];
                        cp = m ? p : 0.f;
                        cn = m ? 0.f : dr*2.f;
                    }
                    cp8[mtb][j] = (short)f2bf(cp);
                    cn8[mtb][j] = (short)f2bf(cn);
                }
            }
            #pragma unroll
            for (int slot = 0; slot < 4; ++slot) {
                int nt = w + slot*4;
                if (nt < 13) {
                    short8 bf = *(const short8*)&Bf[((nt*2 + ks)*64 + lane)*8];
                    acc[0][0][slot] = __builtin_amdgcn_mfma_f32_16x16x32_bf16(cp8[0], bf, acc[0][0][slot], 0,0,0);
                    acc[0][1][slot] = __builtin_amdgcn_mfma_f32_16x16x32_bf16(cp8[1], bf, acc[0][1][slot], 0,0,0);
                    acc[1][0][slot] = __builtin_amdgcn_mfma_f32_16x16x32_bf16(cn8[0], bf, acc[1][0][slot], 0,0,0);
                    acc[1][1][slot] = __builtin_amdgcn_mfma_f32_16x16x32_bf16(cn8[1], bf, acc[1][1][slot], 0,0,0);
                }
            }
        }
    }

    const int col = lane & 15, rg = lane >> 4;
    #pragma unroll
    for (int mat = 0; mat < 2; ++mat)
        #pragma unroll
        for (int mtb = 0; mtb < 2; ++mtb)
            #pragma unroll
            for (int slot = 0; slot < 4; ++slot) {
                int nt = w + slot*4;
                if (nt >= 13) continue;
                #pragma unroll
                for (int r = 0; r < 4; ++r) {
                    int b = mtb*16 + rg*4 + r;
                    gpart[(((size_t)blockIdx.x*2 + mat)*32 + b)*208 + nt*16 + col]
                        = acc[mat][mtb][slot][r];
                }
            }
}

// ---------------------------------------------------------------------------
// Reduce partials: posv/negv [32][208]
// ---------------------------------------------------------------------------
__global__ __launch_bounds__(128) void gred_kernel(
    const float* __restrict__ gpart, float* __restrict__ posv, float* __restrict__ negv)
{
    int o = blockIdx.x*128 + threadIdx.x;
    if (o >= 32*208) return;
    float sp = 0.f, sn = 0.f;
    for (int blk = 0; blk < GVB; ++blk) {
        sp += gpart[((size_t)blk*2 + 0)*(32*208) + o];
        sn += gpart[((size_t)blk*2 + 1)*(32*208) + o];
    }
    posv[o] = sp;
    negv[o] = sn;
}

// ---------------------------------------------------------------------------
// Score: pred[b][e] = sigmoid(9 - sum_d |q[b][d] - e2_emb[e][d]|)
//   469 blocks x 64 e, 256 thr; 4b x 2e per thread; VALU-bound.
// ---------------------------------------------------------------------------
__global__ __launch_bounds__(256) void score_kernel(
    const float* __restrict__ q, const float* __restrict__ e2_emb,
    float* __restrict__ pred)
{
    __shared__ __align__(16) float Qs[32*204];
    const int tid = threadIdx.x;
    const int e0 = blockIdx.x * 64;
    for (int i = tid; i < B*D; i += 256) {
        int b = i / 200, d = i - b*200;
        Qs[b*204 + d] = q[i];
    }
    __syncthreads();

    const int bgrp = tid & 7, egrp = tid >> 3;
    const int b0 = bgrp*4;
    const int ea = e0 + egrp*2, eb = ea + 1;
    const float* r0 = e2_emb + (size_t)(ea < E ? ea : E-1)*200;
    const float* r1 = e2_emb + (size_t)(eb < E ? eb : E-1)*200;

    float acc0[4] = {0.f,0.f,0.f,0.f}, acc1[4] = {0.f,0.f,0.f,0.f};
    #pragma unroll 5
    for (int dc = 0; dc < 200; dc += 8) {
        float4 a0 = *(const float4*)(r0 + dc);
        float4 a1 = *(const float4*)(r0 + dc + 4);
        float4 b0v = *(const float4*)(r1 + dc);
        float4 b1v = *(const float4*)(r1 + dc + 4);
        #pragma unroll
        for (int i = 0; i < 4; ++i) {
            float4 qa = *(const float4*)&Qs[(b0+i)*204 + dc];
            float4 qb = *(const float4*)&Qs[(b0+i)*204 + dc + 4];
            acc0[i] += fabsf(qa.x-a0.x) + fabsf(qa.y-a0.y) + fabsf(qa.z-a0.z) + fabsf(qa.w-a0.w)
                     + fabsf(qb.x-a1.x) + fabsf(qb.y-a1.y) + fabsf(qb.z-a1.z) + fabsf(qb.w-a1.w);
            acc1[i] += fabsf(qa.x-b0v.x) + fabsf(qa.y-b0v.y) + fabsf(qa.z-b0v.z) + fabsf(qa.w-b0v.w)
                     + fabsf(qb.x-b1v.x) + fabsf(qb.y-b1v.y) + fabsf(qb.z-b1v.z) + fabsf(qb.w-b1v.w);
        }
    }
    #pragma unroll
    for (int i = 0; i < 4; ++i) {
        if (ea < E) pred[(size_t)(b0+i)*E + ea] = sigmoidf_(9.0f - acc0[i]);
        if (eb < E) pred[(size_t)(b0+i)*E + eb] = sigmoidf_(9.0f - acc1[i]);
    }
}

// ---------------------------------------------------------------------------
// Final: means -> pos_s/neg_s -> loss  (posv/negv pitch 208)
// ---------------------------------------------------------------------------
__global__ __launch_bounds__(256) void final_kernel(
    const int* __restrict__ e1, const float* __restrict__ q,
    const float* __restrict__ posv, const float* __restrict__ negv,
    const float* __restrict__ psum, const float* __restrict__ isum,
    const float* __restrict__ e2_emb, float* __restrict__ loss_out)
{
    const int tid = threadIdx.x;
    const int b = tid >> 3, dl = tid & 7;
    const int e1b = e1[b];
    const float isp = 1.f / psum[b];
    const float isn = 1.f / isum[b];
    float ps = 0.f, ns = 0.f;
    #pragma unroll
    for (int t = 0; t < 25; ++t) {
        int d = dl*25 + t;
        float e1e = e2_emb[(size_t)e1b*200 + d];
        float pm = 0.3f * (posv[b*208 + d] * isp) + 0.7f * e1e;
        float nm = 0.7f * (negv[b*208 + d] * isn) + 0.3f * e1e;
        float qv = q[b*200 + d];
        ps += fabsf(qv - pm);
        ns += fabsf(qv - nm);
    }
    ps += __shfl_down(ps, 4, 8); ps += __shfl_down(ps, 2, 8); ps += __shfl_down(ps, 1, 8);
    ns += __shfl_down(ns, 4, 8); ns += __shfl_down(ns, 2, 8); ns += __shfl_down(ns, 1, 8);

    __shared__ float PS[B], NS[B];
    if (dl == 0) { PS[b] = ps; NS[b] = ns; }
    __syncthreads();

    float part = 0.f;
    #pragma unroll
    for (int r = 0; r < 4; ++r) {
        int idx = tid + r*256;
        int i = idx >> 5, j = idx & 31;
        float x = NS[j] - PS[i];
        part += fminf(x, 0.f) - log1pf(expf(-fabsf(x)));
    }
    #pragma unroll
    for (int off = 32; off >= 1; off >>= 1) part += __shfl_down(part, off);
    __shared__ float wr[4];
    if ((tid & 63) == 0) wr[tid >> 6] = part;
    __syncthreads();
    if (tid == 0) loss_out[0] = -(wr[0] + wr[1] + wr[2] + wr[3]) * (1.f/1024.f);
}

// ---------------------------------------------------------------------------
extern "C" void kernel_launch(void* const* d_in, const int* in_sizes, int n_in,
                              void* d_out, int out_size, void* d_ws, size_t ws_size,
                              hipStream_t stream)
{
    const int*   e1      = (const int*)d_in[0];
    const int*   rel     = (const int*)d_in[1];
    const int*   e2m     = (const int*)d_in[2];
    const float* emb_e   = (const float*)d_in[3];
    const float* emb_rel = (const float*)d_in[4];
    const float* num_lit = (const float*)d_in[5];
    const float* Wg      = (const float*)d_in[6];
    const float* bg      = (const float*)d_in[7];
    const float* W1      = (const float*)d_in[8];
    const float* W2      = (const float*)d_in[9];
    const float* gbias   = (const float*)d_in[10];
    const float* prob    = (const float*)d_in[11];
    const float* drop    = (const float*)d_in[12];

    float* pred = (float*)d_out;
    float* ws   = (float*)d_ws;

    // workspace layout (float offsets); total ~30.8 MB
    float*          e2_emb = ws;                                   // 6,000,000
    float*          q      = ws + 6000000;                         // 6,400
    unsigned short* whi    = (unsigned short*)(ws + 6006400);      // 106,496 us
    unsigned short* wlo    = (unsigned short*)(ws + 6059648);      // 106,496 us
    float*          gpart  = ws + 6112896;                         // 118*2*6656
    float*          posv   = ws + 7683712;                         // 6,656
    float*          negv   = ws + 7690368;                         // 6,656
    float*          psum   = ws + 7697024;                         // 32
    float*          isum   = ws + 7697056;                         // 32

    wprep_kernel<<<WELEMS/256, 256, 0, stream>>>(Wg, W1, W2, whi, wlo);
    sums_kernel<<<B, 256, 0, stream>>>(e2m, prob, psum, isum);
    gate_kernel<<<(E + 127)/128, 512, 0, stream>>>(emb_e, num_lit, whi, wlo,
                                                   bg, gbias, e2_emb);
    q_kernel<<<1, 256, 0, stream>>>(e1, rel, emb_rel, e2_emb, q);
    gemv_kernel<<<GVB, 256, 0, stream>>>(e2m, prob, drop, e2_emb, gpart);
    gred_kernel<<<(32*208 + 127)/128, 128, 0, stream>>>(gpart, posv, negv);
    score_kernel<<<(E + 63)/64, 256, 0, stream>>>(q, e2_emb, pred);
    final_kernel<<<1, 256, 0, stream>>>(e1, q, posv, negv, psum, isum, e2_emb,
                                        pred + (size_t)B*E);
}

// Round 6
// 268.326 us; speedup vs baseline: 3.1083x; 1.3337x over previous
//
#include <hip/hip_runtime.h>
#include <hip/hip_bf16.h>
#include <cstddef>

constexpr int B = 32, E = 30000, D = 200, L = 50;

using short8 = __attribute__((ext_vector_type(8))) short;
using f32x4  = __attribute__((ext_vector_type(4))) float;

__device__ __forceinline__ float sigmoidf_(float x){ return 1.f/(1.f+__expf(-x)); }
__device__ __forceinline__ float tanhf_(float x){
    float t = __expf(-2.f*fabsf(x));
    return copysignf((1.f-t)/(1.f+t), x);
}
// round-to-nearest-even f32 -> bf16 bits
__device__ __forceinline__ unsigned short f2bf(float x){
    unsigned u = __float_as_uint(x);
    u += 0x7fffu + ((u>>16)&1u);
    return (unsigned short)(u>>16);
}
__device__ __forceinline__ float bf2f(unsigned short h){
    return __uint_as_float(((unsigned)h)<<16);
}

// ---------------------------------------------------------------------------
// W-prep: W' hi/lo bf16 planes in MFMA B-frag order (unchanged layout).
//   n = mat*208 + d  (26 n-tiles of 16); k padded to 256.
//   elem(nt,ks,lane,j) = W[n=nt*16+(lane&15)][k=ks*32+((lane>>4)&3)*8+j]
// ---------------------------------------------------------------------------
constexpr int WELEMS = 26*8*64*8;  // 106496

__global__ __launch_bounds__(256) void wprep_kernel(
    const float* __restrict__ Wg, const float* __restrict__ W1,
    const float* __restrict__ W2,
    unsigned short* __restrict__ whi, unsigned short* __restrict__ wlo)
{
    int idx = blockIdx.x*256 + threadIdx.x;
    if (idx >= WELEMS) return;
    int j = idx & 7, l = (idx>>3)&63, ks = (idx>>9)&7, nt = idx>>12;
    int n = nt*16 + (l&15);
    int k = ks*32 + ((l>>4)&3)*8 + j;
    float v = 0.f;
    if (n < 208) {
        int d = n;
        if (d < 200 && k < 250) v = Wg[d*250 + k];
    } else {
        int d = n - 208;
        if (d < 200) {
            if (k < 200)      v = W1[d*200 + k];
            else if (k < 250) v = W2[d*50 + (k-200)];
        }
    }
    unsigned short h = f2bf(v);
    whi[idx] = h;
    wlo[idx] = f2bf(v - bf2f(h));
}

// ---------------------------------------------------------------------------
// sums v2: 256 blocks (32 b x 8 e-chunks of 3750) -> psum8/isum8 partials
// ---------------------------------------------------------------------------
__global__ __launch_bounds__(256) void sums_kernel(
    const int* __restrict__ e2m, const float* __restrict__ prob,
    float* __restrict__ psum8, float* __restrict__ isum8)
{
    const int tid = threadIdx.x;
    const int b = blockIdx.x >> 3, ch = blockIdx.x & 7;
    const int es = ch * 3750;
    const int*   mrow = e2m  + (size_t)b * E + es;
    const float* prow = prob + (size_t)b * E + es;
    float sp = 0.f, si = 0.f;
    for (int i = tid; i < 3750; i += 256) {
        float m = (float)mrow[i];
        sp = fmaf(m, prow[i], sp);
        si += (1.f - m);
    }
    #pragma unroll
    for (int off = 32; off >= 1; off >>= 1) {
        sp += __shfl_down(sp, off);
        si += __shfl_down(si, off);
    }
    __shared__ float rp[4], ri[4];
    if ((tid & 63) == 0) { rp[tid >> 6] = sp; ri[tid >> 6] = si; }
    __syncthreads();
    if (tid == 0) {
        psum8[b*8 + ch] = rp[0] + rp[1] + rp[2] + rp[3];
        isum8[b*8 + ch] = ri[0] + ri[1] + ri[2] + ri[3];
    }
}

// ---------------------------------------------------------------------------
// Gate v3: MFMA hi/lo split, occupancy + prefetch.
//   Grid 944 = 472 m-blocks (64 rows) x 2 n-halves. 512 thr = 8 waves:
//   wave (mt 0..3, g 0..1): g=0 computes mat0 (pre1), g=1 mat1 (pre2).
//   Each wave: 7 pairs x 2 ks x 3 mfma per chunk; W' loads depth-1 prefetched.
//   n-halves cover pairs {0..6} / {6..12}; overlap pair computed identically.
//   Epilogue: g=1 waves put pre2 in LDS (aliases A tiles), g=0 combines.
// ---------------------------------------------------------------------------
__global__ __launch_bounds__(512) void gate_kernel(
    const float* __restrict__ emb_e, const float* __restrict__ num_lit,
    const unsigned short* __restrict__ whi, const unsigned short* __restrict__ wlo,
    const float* __restrict__ bg, const float* __restrict__ gbias,
    float* __restrict__ e2_emb)
{
    __shared__ __align__(16) char smem[28672];
    unsigned short* Ah = (unsigned short*)smem;            // 8 KB [mt4][ks2][lane64][j8]
    unsigned short* Al = (unsigned short*)(smem + 8192);   // 8 KB
    float* PW = (float*)smem;                              // 28 KB epilogue [mt4][p7][lane64][r4]

    const int tid  = threadIdx.x;
    const int lane = tid & 63;
    const int wid  = tid >> 6;
    const int mt   = wid & 3;
    const int g    = wid >> 2;
    const int mb   = blockIdx.x >> 1;
    const int h    = blockIdx.x & 1;
    const int e0   = mb * 64;
    const int start = h * 6;
    const int ntb  = start + g * 13;

    f32x4 acc[7];
    #pragma unroll
    for (int i = 0; i < 7; ++i) acc[i] = (f32x4){0.f,0.f,0.f,0.f};

    const int srow = tid >> 3;   // 0..63
    const int skq  = tid & 7;    // k-octet
    const int se   = e0 + srow;
    const int aoff = (((srow >> 4)*2 + (skq >> 2))*64 + ((srow & 15) | ((skq & 3) << 4)))*8;

#define WOFF(p, ks) (((size_t)(((ntb + (p))*8 + c*2 + (ks))*64 + lane))*8)

    for (int c = 0; c < 4; ++c) {
        // ---- global loads for A staging (8 k per thread) ----
        float v[8];
        const int k0 = c*64 + skq*8;
        if (se < E) {
            if (k0 + 7 < 200) {
                float4 f0 = *(const float4*)(emb_e + (size_t)se*200 + k0);
                float4 f1 = *(const float4*)(emb_e + (size_t)se*200 + k0 + 4);
                v[0]=f0.x; v[1]=f0.y; v[2]=f0.z; v[3]=f0.w;
                v[4]=f1.x; v[5]=f1.y; v[6]=f1.z; v[7]=f1.w;
            } else {  // k0 >= 200 (octets are multiples of 8; no mixed case)
                #pragma unroll
                for (int z = 0; z < 8; ++z) {
                    int kz = k0 + z;
                    v[z] = (kz < 250) ? num_lit[(size_t)se*50 + (kz - 200)] : 0.f;
                }
            }
        } else {
            #pragma unroll
            for (int z = 0; z < 8; ++z) v[z] = 0.f;
        }
        if (c) __syncthreads();          // WAR vs previous chunk's frag reads
        short8 hv, lv;
        #pragma unroll
        for (int z = 0; z < 8; ++z) {
            unsigned short hh = f2bf(v[z]);
            hv[z] = (short)hh;
            lv[z] = (short)f2bf(v[z] - bf2f(hh));
        }
        *(short8*)&Ah[aoff] = hv;
        *(short8*)&Al[aoff] = lv;
        __syncthreads();

        // ---- issue first W' loads, then A frag reads ----
        short8 pwh[2][2], pwl[2][2];
        pwh[0][0] = *(const short8*)(whi + WOFF(0,0));
        pwh[0][1] = *(const short8*)(whi + WOFF(0,1));
        pwl[0][0] = *(const short8*)(wlo + WOFF(0,0));
        pwl[0][1] = *(const short8*)(wlo + WOFF(0,1));

        short8 xh[2], xl[2];
        #pragma unroll
        for (int ks = 0; ks < 2; ++ks) {
            int fo = ((mt*2 + ks)*64 + lane)*8;
            xh[ks] = *(const short8*)&Ah[fo];
            xl[ks] = *(const short8*)&Al[fo];
        }

        #pragma unroll
        for (int p = 0; p < 7; ++p) {
            const int cur = p & 1, nxt = cur ^ 1;
            if (p < 6) {
                pwh[nxt][0] = *(const short8*)(whi + WOFF(p+1,0));
                pwh[nxt][1] = *(const short8*)(whi + WOFF(p+1,1));
                pwl[nxt][0] = *(const short8*)(wlo + WOFF(p+1,0));
                pwl[nxt][1] = *(const short8*)(wlo + WOFF(p+1,1));
            }
            #pragma unroll
            for (int ks = 0; ks < 2; ++ks) {
                acc[p] = __builtin_amdgcn_mfma_f32_16x16x32_bf16(xh[ks], pwh[cur][ks], acc[p], 0,0,0);
                acc[p] = __builtin_amdgcn_mfma_f32_16x16x32_bf16(xl[ks], pwh[cur][ks], acc[p], 0,0,0);
                acc[p] = __builtin_amdgcn_mfma_f32_16x16x32_bf16(xh[ks], pwl[cur][ks], acc[p], 0,0,0);
            }
        }
    }
#undef WOFF

    // ---- epilogue: exchange pre2 via LDS, combine in g=0 waves ----
    __syncthreads();
    if (g == 1) {
        #pragma unroll
        for (int p = 0; p < 7; ++p)
            *(f32x4*)&PW[((mt*7 + p)*64 + lane)*4] = acc[p];
    }
    __syncthreads();
    if (g == 0) {
        const int col = lane & 15, rg = lane >> 4;
        #pragma unroll
        for (int p = 0; p < 7; ++p) {
            int d = (start + p)*16 + col;
            if (d >= 200) continue;
            float bgd = bg[d], gbd = gbias[d];
            f32x4 p2 = *(const f32x4*)&PW[((mt*7 + p)*64 + lane)*4];
            #pragma unroll
            for (int r = 0; r < 4; ++r) {
                int e = e0 + mt*16 + rg*4 + r;
                if (e >= E) continue;
                float pre1 = acc[p][r] + bgd;
                float pre2 = p2[r] + gbd;
                float gt = sigmoidf_(pre2);
                float t  = tanhf_(pre1);
                float emb = emb_e[(size_t)e*200 + d];
                e2_emb[(size_t)e*200 + d] = (1.f - gt)*emb + gt*t;
            }
        }
    }
}

// ---------------------------------------------------------------------------
// K_q
// ---------------------------------------------------------------------------
__global__ __launch_bounds__(256) void q_kernel(
    const int* __restrict__ e1, const int* __restrict__ rel,
    const float* __restrict__ emb_rel, const float* __restrict__ e2_emb,
    float* __restrict__ q)
{
    int tid = threadIdx.x;
    for (int idx = tid; idx < B * D; idx += 256) {
        int b = idx / D, d = idx % D;
        q[idx] = e2_emb[(size_t)e1[b] * D + d] + emb_rel[(size_t)rel[b] * D + d];
    }
}

// ---------------------------------------------------------------------------
// GEMV v3 via MFMA: 235 blocks x 128 e (2 chunks of 64).
//   Coefficients staged coalesced -> LDS A-frags (fixes b-strided loads).
// ---------------------------------------------------------------------------
constexpr int GVB = 235;

__global__ __launch_bounds__(256) void gemv_kernel(
    const int* __restrict__ e2m, const float* __restrict__ prob,
    const float* __restrict__ drop, const float* __restrict__ e2_emb,
    float* __restrict__ gpart)
{
    __shared__ unsigned short Bf[13312];                // [nt13][ks2][lane64][j8]
    __shared__ unsigned short Acp[2048], Acn[2048];     // [mtb2][ks2][lane64][j8]
    const int tid = threadIdx.x, lane = tid & 63, w = tid >> 6;
    const int e0 = blockIdx.x * 128;

    f32x4 acc[2][2][4];
    #pragma unroll
    for (int a = 0; a < 2; ++a)
        #pragma unroll
        for (int m = 0; m < 2; ++m)
            #pragma unroll
            for (int s = 0; s < 4; ++s) acc[a][m][s] = (f32x4){0.f,0.f,0.f,0.f};

    for (int c = 0; c < 2; ++c) {
        const int ec = e0 + c*64;
        if (c) __syncthreads();

        // ---- stage coefficients coalesced -> A-frag layout ----
        {
            const int bb = tid >> 3, part = tid & 7;
            const int eb = ec + part*8;
            float cp[8], cn[8];
            size_t base = (size_t)bb * E + eb;
            if (eb + 7 < E) {
                int4   m0 = *(const int4*)(e2m + base),   m1 = *(const int4*)(e2m + base + 4);
                float4 p0 = *(const float4*)(prob + base), p1 = *(const float4*)(prob + base + 4);
                float4 d0 = *(const float4*)(drop + base), d1 = *(const float4*)(drop + base + 4);
                cp[0]=m0.x?p0.x:0.f; cn[0]=m0.x?0.f:2.f*d0.x;
                cp[1]=m0.y?p0.y:0.f; cn[1]=m0.y?0.f:2.f*d0.y;
                cp[2]=m0.z?p0.z:0.f; cn[2]=m0.z?0.f:2.f*d0.z;
                cp[3]=m0.w?p0.w:0.f; cn[3]=m0.w?0.f:2.f*d0.w;
                cp[4]=m1.x?p1.x:0.f; cn[4]=m1.x?0.f:2.f*d1.x;
                cp[5]=m1.y?p1.y:0.f; cn[5]=m1.y?0.f:2.f*d1.y;
                cp[6]=m1.z?p1.z:0.f; cn[6]=m1.z?0.f:2.f*d1.z;
                cp[7]=m1.w?p1.w:0.f; cn[7]=m1.w?0.f:2.f*d1.w;
            } else {
                #pragma unroll
                for (int j = 0; j < 8; ++j) {
                    int e = eb + j;
                    cp[j] = 0.f; cn[j] = 0.f;
                    if (e < E) {
                        int m = e2m[base + j];
                        cp[j] = m ? prob[base + j] : 0.f;
                        cn[j] = m ? 0.f : 2.f * drop[base + j];
                    }
                }
            }
            short8 scp, scn;
            #pragma unroll
            for (int j = 0; j < 8; ++j) { scp[j] = (short)f2bf(cp[j]); scn[j] = (short)f2bf(cn[j]); }
            int off = (((bb >> 4)*2 + (part >> 2))*64 + ((bb & 15) | ((part & 3) << 4)))*8;
            *(short8*)&Acp[off] = scp;
            *(short8*)&Acn[off] = scn;
        }

        // ---- stage e2_emb chunk into B-frag layout ----
        for (int s = tid; s < 3328; s += 256) {
            int el = s / 52, d4 = (s - el*52)*4;
            int e = ec + el;
            float4 f = make_float4(0.f,0.f,0.f,0.f);
            if (e < E && d4 < 200) f = *(const float4*)(e2_emb + (size_t)e*200 + d4);
            int ks = el >> 5, lp = (el >> 3) & 3, j = el & 7;
            float fv[4] = {f.x, f.y, f.z, f.w};
            #pragma unroll
            for (int z = 0; z < 4; ++z) {
                int d = d4 + z;
                Bf[(((d >> 4)*2 + ks)*64 + ((d & 15) | (lp << 4)))*8 + j] = f2bf(fv[z]);
            }
        }
        __syncthreads();

        // ---- MFMA ----
        short8 cpA[2][2], cnA[2][2];
        #pragma unroll
        for (int mtb = 0; mtb < 2; ++mtb)
            #pragma unroll
            for (int ks = 0; ks < 2; ++ks) {
                int fo = ((mtb*2 + ks)*64 + lane)*8;
                cpA[mtb][ks] = *(const short8*)&Acp[fo];
                cnA[mtb][ks] = *(const short8*)&Acn[fo];
            }
        #pragma unroll
        for (int ks = 0; ks < 2; ++ks)
            #pragma unroll
            for (int slot = 0; slot < 4; ++slot) {
                int nt = w + slot*4;
                if (nt < 13) {
                    short8 bf = *(const short8*)&Bf[((nt*2 + ks)*64 + lane)*8];
                    acc[0][0][slot] = __builtin_amdgcn_mfma_f32_16x16x32_bf16(cpA[0][ks], bf, acc[0][0][slot], 0,0,0);
                    acc[0][1][slot] = __builtin_amdgcn_mfma_f32_16x16x32_bf16(cpA[1][ks], bf, acc[0][1][slot], 0,0,0);
                    acc[1][0][slot] = __builtin_amdgcn_mfma_f32_16x16x32_bf16(cnA[0][ks], bf, acc[1][0][slot], 0,0,0);
                    acc[1][1][slot] = __builtin_amdgcn_mfma_f32_16x16x32_bf16(cnA[1][ks], bf, acc[1][1][slot], 0,0,0);
                }
            }
    }

    const int col = lane & 15, rg = lane >> 4;
    #pragma unroll
    for (int mat = 0; mat < 2; ++mat)
        #pragma unroll
        for (int mtb = 0; mtb < 2; ++mtb)
            #pragma unroll
            for (int slot = 0; slot < 4; ++slot) {
                int nt = w + slot*4;
                if (nt >= 13) continue;
                int d = nt*16 + col;
                if (d >= 200) continue;
                #pragma unroll
                for (int r = 0; r < 4; ++r) {
                    int b = mtb*16 + rg*4 + r;
                    gpart[(((size_t)blockIdx.x*2 + mat)*32 + b)*200 + d]
                        = acc[mat][mtb][slot][r];
                }
            }
}

// ---------------------------------------------------------------------------
// Reduce partials: posv/negv [32][200]
// ---------------------------------------------------------------------------
__global__ __launch_bounds__(128) void gred_kernel(
    const float* __restrict__ gpart, float* __restrict__ posv, float* __restrict__ negv)
{
    int o = blockIdx.x*128 + threadIdx.x;     // < 6400
    float sp = 0.f, sn = 0.f;
    #pragma unroll 4
    for (int blk = 0; blk < GVB; ++blk) {
        sp += gpart[((size_t)blk*2 + 0)*6400 + o];
        sn += gpart[((size_t)blk*2 + 1)*6400 + o];
    }
    posv[o] = sp;
    negv[o] = sn;
}

// ---------------------------------------------------------------------------
// Score: pred[b][e] = sigmoid(9 - sum_d |q[b][d] - e2_emb[e][d]|)
// ---------------------------------------------------------------------------
__global__ __launch_bounds__(256) void score_kernel(
    const float* __restrict__ q, const float* __restrict__ e2_emb,
    float* __restrict__ pred)
{
    __shared__ __align__(16) float Qs[32*204];
    const int tid = threadIdx.x;
    const int e0 = blockIdx.x * 64;
    for (int i = tid; i < B*D; i += 256) {
        int b = i / 200, d = i - b*200;
        Qs[b*204 + d] = q[i];
    }
    __syncthreads();

    const int bgrp = tid & 7, egrp = tid >> 3;
    const int b0 = bgrp*4;
    const int ea = e0 + egrp*2, eb = ea + 1;
    const float* r0 = e2_emb + (size_t)(ea < E ? ea : E-1)*200;
    const float* r1 = e2_emb + (size_t)(eb < E ? eb : E-1)*200;

    float acc0[4] = {0.f,0.f,0.f,0.f}, acc1[4] = {0.f,0.f,0.f,0.f};
    #pragma unroll 5
    for (int dc = 0; dc < 200; dc += 8) {
        float4 a0 = *(const float4*)(r0 + dc);
        float4 a1 = *(const float4*)(r0 + dc + 4);
        float4 b0v = *(const float4*)(r1 + dc);
        float4 b1v = *(const float4*)(r1 + dc + 4);
        #pragma unroll
        for (int i = 0; i < 4; ++i) {
            float4 qa = *(const float4*)&Qs[(b0+i)*204 + dc];
            float4 qb = *(const float4*)&Qs[(b0+i)*204 + dc + 4];
            acc0[i] += fabsf(qa.x-a0.x) + fabsf(qa.y-a0.y) + fabsf(qa.z-a0.z) + fabsf(qa.w-a0.w)
                     + fabsf(qb.x-a1.x) + fabsf(qb.y-a1.y) + fabsf(qb.z-a1.z) + fabsf(qb.w-a1.w);
            acc1[i] += fabsf(qa.x-b0v.x) + fabsf(qa.y-b0v.y) + fabsf(qa.z-b0v.z) + fabsf(qa.w-b0v.w)
                     + fabsf(qb.x-b1v.x) + fabsf(qb.y-b1v.y) + fabsf(qb.z-b1v.z) + fabsf(qb.w-b1v.w);
        }
    }
    #pragma unroll
    for (int i = 0; i < 4; ++i) {
        if (ea < E) pred[(size_t)(b0+i)*E + ea] = sigmoidf_(9.0f - acc0[i]);
        if (eb < E) pred[(size_t)(b0+i)*E + eb] = sigmoidf_(9.0f - acc1[i]);
    }
}

// ---------------------------------------------------------------------------
// Final: fold psum8/isum8, means -> pos_s/neg_s -> loss (posv pitch 200)
// ---------------------------------------------------------------------------
__global__ __launch_bounds__(256) void final_kernel(
    const int* __restrict__ e1, const float* __restrict__ q,
    const float* __restrict__ posv, const float* __restrict__ negv,
    const float* __restrict__ psum8, const float* __restrict__ isum8,
    const float* __restrict__ e2_emb, float* __restrict__ loss_out)
{
    const int tid = threadIdx.x;
    __shared__ float SP[32], SI[32];
    if (tid < 32) {
        float s = 0.f, t = 0.f;
        #pragma unroll
        for (int k = 0; k < 8; ++k) { s += psum8[tid*8 + k]; t += isum8[tid*8 + k]; }
        SP[tid] = s; SI[tid] = t;
    }
    __syncthreads();

    const int b = tid >> 3, dl = tid & 7;
    const int e1b = e1[b];
    const float isp = 1.f / SP[b];
    const float isn = 1.f / SI[b];
    float ps = 0.f, ns = 0.f;
    #pragma unroll
    for (int t = 0; t < 25; ++t) {
        int d = dl*25 + t;
        float e1e = e2_emb[(size_t)e1b*200 + d];
        float pm = 0.3f * (posv[b*200 + d] * isp) + 0.7f * e1e;
        float nm = 0.7f * (negv[b*200 + d] * isn) + 0.3f * e1e;
        float qv = q[b*200 + d];
        ps += fabsf(qv - pm);
        ns += fabsf(qv - nm);
    }
    ps += __shfl_down(ps, 4, 8); ps += __shfl_down(ps, 2, 8); ps += __shfl_down(ps, 1, 8);
    ns += __shfl_down(ns, 4, 8); ns += __shfl_down(ns, 2, 8); ns += __shfl_down(ns, 1, 8);

    __shared__ float PS[B], NS[B];
    if (dl == 0) { PS[b] = ps; NS[b] = ns; }
    __syncthreads();

    float part = 0.f;
    #pragma unroll
    for (int r = 0; r < 4; ++r) {
        int idx = tid + r*256;
        int i = idx >> 5, j = idx & 31;
        float x = NS[j] - PS[i];
        part += fminf(x, 0.f) - log1pf(expf(-fabsf(x)));
    }
    #pragma unroll
    for (int off = 32; off >= 1; off >>= 1) part += __shfl_down(part, off);
    __shared__ float wr[4];
    if ((tid & 63) == 0) wr[tid >> 6] = part;
    __syncthreads();
    if (tid == 0) loss_out[0] = -(wr[0] + wr[1] + wr[2] + wr[3]) * (1.f/1024.f);
}

// ---------------------------------------------------------------------------
extern "C" void kernel_launch(void* const* d_in, const int* in_sizes, int n_in,
                              void* d_out, int out_size, void* d_ws, size_t ws_size,
                              hipStream_t stream)
{
    const int*   e1      = (const int*)d_in[0];
    const int*   rel     = (const int*)d_in[1];
    const int*   e2m     = (const int*)d_in[2];
    const float* emb_e   = (const float*)d_in[3];
    const float* emb_rel = (const float*)d_in[4];
    const float* num_lit = (const float*)d_in[5];
    const float* Wg      = (const float*)d_in[6];
    const float* bg      = (const float*)d_in[7];
    const float* W1      = (const float*)d_in[8];
    const float* W2      = (const float*)d_in[9];
    const float* gbias   = (const float*)d_in[10];
    const float* prob    = (const float*)d_in[11];
    const float* drop    = (const float*)d_in[12];

    float* pred = (float*)d_out;
    float* ws   = (float*)d_ws;

    // workspace layout (float offsets); total ~36.5 MB
    float*          e2_emb = ws;                                   // 6,000,000
    float*          q      = ws + 6000000;                         // 6,400
    unsigned short* whi    = (unsigned short*)(ws + 6006400);      // 106,496 us
    unsigned short* wlo    = (unsigned short*)(ws + 6059648);      // 106,496 us
    float*          gpart  = ws + 6112896;                         // 235*2*6400
    float*          posv   = ws + 9120896;                         // 6,400
    float*          negv   = ws + 9127296;                         // 6,400
    float*          psum8  = ws + 9133696;                         // 256
    float*          isum8  = ws + 9133952;                         // 256

    wprep_kernel<<<WELEMS/256, 256, 0, stream>>>(Wg, W1, W2, whi, wlo);
    sums_kernel<<<256, 256, 0, stream>>>(e2m, prob, psum8, isum8);
    gate_kernel<<<944, 512, 0, stream>>>(emb_e, num_lit, whi, wlo, bg, gbias, e2_emb);
    q_kernel<<<1, 256, 0, stream>>>(e1, rel, emb_rel, e2_emb, q);
    gemv_kernel<<<GVB, 256, 0, stream>>>(e2m, prob, drop, e2_emb, gpart);
    gred_kernel<<<50, 128, 0, stream>>>(gpart, posv, negv);
    score_kernel<<<(E + 63)/64, 256, 0, stream>>>(q, e2_emb, pred);
    final_kernel<<<1, 256, 0, stream>>>(e1, q, posv, negv, psum8, isum8, e2_emb,
                                        pred + (size_t)B*E);
}